// Round 1
// baseline (3036.088 us; speedup 1.0000x reference)
//
#include <hip/hip_runtime.h>

// Periodic 2D NS projection step, 512x512, fp32.
// Reference semantics:
//   ddx = central diff along axis -2 (row index i, stride W)
//   ddy = central diff along axis -1 (col index j, stride 1)
//   adv[c]     = X0*ddx(X[c]) + X1*ddy(X[c])
//   partial[c] = -adv[c] + NU*lap(X[c]) + forcing[c]
//   B          = (ddx(p0) + ddy(p1)) / DT          (RHO=1, DX=1)
//   phi0 = B;  phi <- (nsum(phi) - B)/4   x1000
//   out[c]     = partial[c] - dd{x,y}(phi)

#define HH 512
#define WW 512
#define NCELL (HH * WW)
#define NU_C 0.1f
#define INV_DT 10.0f   // 1/DT, DT=0.1

__device__ __forceinline__ void cell_idx(int idx, int& i, int& j,
                                         int& ip, int& im, int& jp, int& jm) {
    i = idx >> 9;        // /512
    j = idx & 511;
    ip = (i + 1) & 511;
    im = (i + 511) & 511;
    jp = (j + 1) & 511;
    jm = (j + 511) & 511;
}

__global__ void partial_kernel(const float* __restrict__ X,
                               const float* __restrict__ F,
                               float* __restrict__ p) {
    int idx = blockIdx.x * blockDim.x + threadIdx.x;
    if (idx >= NCELL) return;
    int i, j, ip, im, jp, jm;
    cell_idx(idx, i, j, ip, im, jp, jm);

    const float* X0 = X;
    const float* X1 = X + NCELL;
    float x0c = X0[idx];
    float x1c = X1[idx];

#pragma unroll
    for (int c = 0; c < 2; ++c) {
        const float* Xc = X + c * NCELL;
        float xc  = Xc[idx];
        float xip = Xc[ip * WW + j];
        float xim = Xc[im * WW + j];
        float xjp = Xc[i * WW + jp];
        float xjm = Xc[i * WW + jm];
        float ddx = (xip - xim) * 0.5f;
        float ddy = (xjp - xjm) * 0.5f;
        float lap = xip + xim + xjp + xjm - 4.0f * xc;
        float adv = x0c * ddx + x1c * ddy;
        p[c * NCELL + idx] = -adv + NU_C * lap + F[c * NCELL + idx];
    }
}

__global__ void binit_kernel(const float* __restrict__ p,
                             float* __restrict__ B,
                             float* __restrict__ phi) {
    int idx = blockIdx.x * blockDim.x + threadIdx.x;
    if (idx >= NCELL) return;
    int i, j, ip, im, jp, jm;
    cell_idx(idx, i, j, ip, im, jp, jm);

    const float* p0 = p;
    const float* p1 = p + NCELL;
    float ddx_p0 = (p0[ip * WW + j] - p0[im * WW + j]) * 0.5f;
    float ddy_p1 = (p1[i * WW + jp] - p1[i * WW + jm]) * 0.5f;
    float b = (ddx_p0 + ddy_p1) * INV_DT;
    B[idx] = b;
    phi[idx] = b;   // phi_0 = B
}

__global__ void jacobi_kernel(const float* __restrict__ src,
                              const float* __restrict__ B,
                              float* __restrict__ dst) {
    int idx = blockIdx.x * blockDim.x + threadIdx.x;
    if (idx >= NCELL) return;
    int i, j, ip, im, jp, jm;
    cell_idx(idx, i, j, ip, im, jp, jm);

    float nsum = src[ip * WW + j] + src[im * WW + j]
               + src[i * WW + jp] + src[i * WW + jm];
    dst[idx] = (nsum - B[idx]) * 0.25f;
}

__global__ void out_kernel(const float* __restrict__ p,
                           const float* __restrict__ phi,
                           float* __restrict__ out) {
    int idx = blockIdx.x * blockDim.x + threadIdx.x;
    if (idx >= NCELL) return;
    int i, j, ip, im, jp, jm;
    cell_idx(idx, i, j, ip, im, jp, jm);

    float gx = (phi[ip * WW + j] - phi[im * WW + j]) * 0.5f;
    float gy = (phi[i * WW + jp] - phi[i * WW + jm]) * 0.5f;
    out[idx]         = p[idx]         - gx;   // RHO = 1
    out[NCELL + idx] = p[NCELL + idx] - gy;
}

extern "C" void kernel_launch(void* const* d_in, const int* in_sizes, int n_in,
                              void* d_out, int out_size, void* d_ws, size_t ws_size,
                              hipStream_t stream) {
    // d_in[0] = t (unused), d_in[1] = X (2,1,512,512) f32, d_in[2] = forcing
    const float* X = (const float*)d_in[1];
    const float* F = (const float*)d_in[2];
    float* out = (float*)d_out;
    float* ws  = (float*)d_ws;

    float* p    = ws;              // 2*NCELL
    float* B    = ws + 2 * NCELL;  // NCELL
    float* phiA = ws + 3 * NCELL;  // NCELL
    float* phiB = ws + 4 * NCELL;  // NCELL

    dim3 blk(256);
    dim3 grd(NCELL / 256);

    partial_kernel<<<grd, blk, 0, stream>>>(X, F, p);
    binit_kernel<<<grd, blk, 0, stream>>>(p, B, phiA);

    // 1000 Jacobi sweeps, ping-pong. it=0: A->B ... it=999: B->A.
    for (int it = 0; it < 1000; ++it) {
        float* src = (it & 1) ? phiB : phiA;
        float* dst = (it & 1) ? phiA : phiB;
        jacobi_kernel<<<grd, blk, 0, stream>>>(src, B, dst);
    }
    // result in phiA (1000 even)

    out_kernel<<<grd, blk, 0, stream>>>(p, phiA, out);
}

// Round 2
// 89.821 us; speedup vs baseline: 33.8017x; 33.8017x over previous
//
#include <hip/hip_runtime.h>
#include <math.h>

// Spectral solve of the 1000-step Jacobi relaxation (exact linear-algebra
// identity with the iterate, diagonal in Fourier space).
//
//   partial = -adv + NU*lap(X) + F            (real space, 5-pt stencils)
//   B_hat   = 10*i*(sx*p0_hat + sy*p1_hat)    sx=sin(2*pi*ki/512), sy=sin(2*pi*kj/512)
//   phi_N_hat = B_hat * M,  M = r^N - (1-r^N)/(4-s),  r=s/4, s=2cos(a_i)+2cos(a_j)
//   g_hat_x = i*sx*phi_hat = -10*M*sx*(sx*p0_hat+sy*p1_hat)   (real coefficient)
//   out = partial - (gx, gy)
//
// Both real fields packed as z = p0 + i*p1 -> ONE complex 2D FFT each way:
//   W(k) = (beta/2)*[(sx^2+sy^2)*Z(k) + (sx+i*sy)^2*conj(Z(-k))],
//   beta = -10*M/512^2 (ifft scale folded in; beta=0 at k=0 — gradient kills
//   the DC mode so its value is arbitrary),   w = ifft2(W) = gx + i*gy.

#define HH 512
#define WW 512
#define NCELL (HH * WW)
#define NU_C 0.1f
#define INV_DT 10.0f
#define PI_F 3.14159265358979323846f

// ---------------------------------------------------------------- stencil ops
__device__ __forceinline__ void cell_idx(int idx, int& i, int& j,
                                         int& ip, int& im, int& jp, int& jm) {
    i = idx >> 9;
    j = idx & 511;
    ip = (i + 1) & 511;
    im = (i + 511) & 511;
    jp = (j + 1) & 511;
    jm = (j + 511) & 511;
}

__global__ __launch_bounds__(256) void partial_kernel(const float* __restrict__ X,
                                                      const float* __restrict__ F,
                                                      float* __restrict__ p) {
    int idx = blockIdx.x * blockDim.x + threadIdx.x;
    int i, j, ip, im, jp, jm;
    cell_idx(idx, i, j, ip, im, jp, jm);

    float x0c = X[idx];
    float x1c = X[NCELL + idx];

#pragma unroll
    for (int c = 0; c < 2; ++c) {
        const float* Xc = X + c * NCELL;
        float xc  = Xc[idx];
        float xip = Xc[ip * WW + j];
        float xim = Xc[im * WW + j];
        float xjp = Xc[i * WW + jp];
        float xjm = Xc[i * WW + jm];
        float ddx = (xip - xim) * 0.5f;
        float ddy = (xjp - xjm) * 0.5f;
        float lap = xip + xim + xjp + xjm - 4.0f * xc;
        float adv = x0c * ddx + x1c * ddy;
        p[c * NCELL + idx] = -adv + NU_C * lap + F[c * NCELL + idx];
    }
}

// ---------------------------------------------------------------- FFT core
// 512-pt radix-2 Stockham (autosort), 256 threads = 1 butterfly each per
// stage, LDS ping-pong. tw[q] = cis(sign * -pi * q / 256); stage s uses
// tw[p << (8-s)]. Returns pointer to the buffer holding the result.
// Caller must __syncthreads() after filling `a` and after building `tw`.
__device__ float2* fft512_lds(float2* a, float2* b, const float2* tw, int t) {
    float2* src = a;
    float2* dst = b;
#pragma unroll
    for (int s = 0; s < 9; ++s) {
        int Ls = 1 << s;
        int pp = t & (Ls - 1);
        int q  = t >> s;
        float2 w = tw[pp << (8 - s)];
        float2 xa = src[q * Ls + pp];
        float2 xb = src[q * Ls + pp + 256];
        float2 wb;
        wb.x = w.x * xb.x - w.y * xb.y;
        wb.y = w.x * xb.y + w.y * xb.x;
        dst[q * 2 * Ls + pp]      = make_float2(xa.x + wb.x, xa.y + wb.y);
        dst[q * 2 * Ls + pp + Ls] = make_float2(xa.x - wb.x, xa.y - wb.y);
        float2* tmp = src; src = dst; dst = tmp;
        __syncthreads();
    }
    return src;
}

__device__ __forceinline__ void build_tw(float2* tw, int t, float sign) {
    float ang = sign * (-PI_F) * (float)t * (1.0f / 256.0f);
    float sn, cs;
    sincosf(ang, &sn, &cs);
    tw[t] = make_float2(cs, sn);
}

// ------------------------------------------------- K2: forward FFT over rows
// z = p0 + i*p1; FFT along j (contiguous). One block per row i.
__global__ __launch_bounds__(256) void fwd_rows(const float* __restrict__ p,
                                                float2* __restrict__ Z) {
    __shared__ float2 bufA[512], bufB[512], tw[256];
    int i = blockIdx.x, t = threadIdx.x;
    build_tw(tw, t, 1.0f);
    bufA[t]       = make_float2(p[i * WW + t],       p[NCELL + i * WW + t]);
    bufA[t + 256] = make_float2(p[i * WW + t + 256], p[NCELL + i * WW + t + 256]);
    __syncthreads();
    float2* res = fft512_lds(bufA, bufB, tw, t);
    Z[i * WW + t]       = res[t];
    Z[i * WW + t + 256] = res[t + 256];
}

// ---------------------------------------------- K3: forward FFT over columns
// FFT along i for fixed j. One block per column j (strided global access;
// data is L2-resident).
__global__ __launch_bounds__(256) void fwd_cols(const float2* __restrict__ Z,
                                                float2* __restrict__ Z2) {
    __shared__ float2 bufA[512], bufB[512], tw[256];
    int j = blockIdx.x, t = threadIdx.x;
    build_tw(tw, t, 1.0f);
    bufA[t]       = Z[t * WW + j];
    bufA[t + 256] = Z[(t + 256) * WW + j];
    __syncthreads();
    float2* res = fft512_lds(bufA, bufB, tw, t);
    Z2[t * WW + j]       = res[t];
    Z2[(t + 256) * WW + j] = res[t + 256];
}

// ------------------------- K4: pointwise multiplier + inverse FFT over columns
__global__ __launch_bounds__(256) void pw_inv_cols(const float2* __restrict__ Z2,
                                                   float2* __restrict__ W1) {
    __shared__ float2 bufA[512], bufB[512], tw[256];
    int j = blockIdx.x, t = threadIdx.x;        // j = kj
    int mj = (WW - j) & 511;
    build_tw(tw, t, -1.0f);                     // inverse twiddles

    double aj = 2.0 * M_PI * (double)j / 512.0;
    double cj = cos(aj);
    float  syf = (float)sin(aj);

#pragma unroll
    for (int e = 0; e < 2; ++e) {
        int ki = t + e * 256;
        int mi = (HH - ki) & 511;
        float2 z  = Z2[ki * WW + j];
        float2 zm = Z2[mi * WW + mj];

        double ai = 2.0 * M_PI * (double)ki / 512.0;
        double s4 = 2.0 * cos(ai) + 2.0 * cj;
        double beta = 0.0;
        if (!(ki == 0 && j == 0)) {
            double r  = 0.25 * s4;
            double rN = pow(fabs(r), 1000.0);       // N even -> r^N = |r|^N
            double M  = rN - (1.0 - rN) / (4.0 - s4);
            beta = -10.0 * M / (512.0 * 512.0);     // INV_DT * M, ifft scale folded
        }
        float sx = (float)sin(ai);
        float su  = sx * sx + syf * syf;
        float u2x = sx * sx - syf * syf;
        float u2y = 2.0f * sx * syf;
        // W = (beta/2) * (su*z + u2*conj(zm))
        float cx = zm.x, cy = -zm.y;
        float tx = u2x * cx - u2y * cy;
        float ty = u2x * cy + u2y * cx;
        float bh = (float)(0.5 * beta);
        bufA[ki] = make_float2(bh * (su * z.x + tx), bh * (su * z.y + ty));
    }
    __syncthreads();
    float2* res = fft512_lds(bufA, bufB, tw, t);
    W1[t * WW + j]         = res[t];
    W1[(t + 256) * WW + j] = res[t + 256];
}

// --------------------------------- K5: inverse FFT over rows + final output
__global__ __launch_bounds__(256) void inv_rows_out(const float2* __restrict__ W1,
                                                    const float* __restrict__ p,
                                                    float* __restrict__ out) {
    __shared__ float2 bufA[512], bufB[512], tw[256];
    int i = blockIdx.x, t = threadIdx.x;
    build_tw(tw, t, -1.0f);
    bufA[t]       = W1[i * WW + t];
    bufA[t + 256] = W1[i * WW + t + 256];
    __syncthreads();
    float2* res = fft512_lds(bufA, bufB, tw, t);
#pragma unroll
    for (int e = 0; e < 2; ++e) {
        int j = t + e * 256;
        float2 w = res[j];
        out[i * WW + j]         = p[i * WW + j]         - w.x;  // p0 - gx
        out[NCELL + i * WW + j] = p[NCELL + i * WW + j] - w.y;  // p1 - gy
    }
}

// ---------------------------------------------------------------------------
extern "C" void kernel_launch(void* const* d_in, const int* in_sizes, int n_in,
                              void* d_out, int out_size, void* d_ws, size_t ws_size,
                              hipStream_t stream) {
    const float* X = (const float*)d_in[1];
    const float* F = (const float*)d_in[2];
    float* out = (float*)d_out;
    float* ws  = (float*)d_ws;

    float*  p    = ws;                         // 2*NCELL floats (2 MB)
    float2* bufZ = (float2*)(ws + 2 * NCELL);  // NCELL float2 (2 MB)
    float2* bufZ2 = bufZ + NCELL;              // NCELL float2 (2 MB)
    // W1 reuses bufZ (row-FFT output dead after fwd_cols)

    dim3 blk(256);
    partial_kernel<<<dim3(NCELL / 256), blk, 0, stream>>>(X, F, p);
    fwd_rows     <<<dim3(HH), blk, 0, stream>>>(p, bufZ);
    fwd_cols     <<<dim3(WW), blk, 0, stream>>>(bufZ, bufZ2);
    pw_inv_cols  <<<dim3(WW), blk, 0, stream>>>(bufZ2, bufZ);
    inv_rows_out <<<dim3(HH), blk, 0, stream>>>(bufZ, p, out);
}